// Round 3
// baseline (1096.155 us; speedup 1.0000x reference)
//
#include <hip/hip_runtime.h>
#include <math.h>

#define H 1024
#define V 50257
#define S 8192
#define NROWBLK ((V + 3) / 4)   // 12565

// counter layout (ints at ws start):
// [0] kA master  [1] kB v-ticket  [2] vdone  [3] sdone master
// [4] ctx_done   [5] ctx_flag     [8..23] kA sub  [24..39] sdone sub
// [40..47] ctx lane tickets
#define CNT_INTS 48

__device__ __forceinline__ float wave_reduce_sum(float v) {
  #pragma unroll
  for (int o = 32; o > 0; o >>= 1) v += __shfl_down(v, o, 64);
  return v;
}

// ---------------- K_A: gates + GRU (last-finisher) ----------------
__global__ __launch_bounds__(256) void k_gates_gru(
    const float* __restrict__ Wih, const float* __restrict__ Whh,
    const float* __restrict__ bih, const float* __restrict__ bhh,
    const float* __restrict__ emb, const int* __restrict__ word,
    const float* __restrict__ h0, const float* __restrict__ battn,
    float* __restrict__ gi, float* __restrict__ gh,
    float* __restrict__ xv, float* __restrict__ v, float* __restrict__ c0,
    float* __restrict__ ctx_p, float* __restrict__ out_h, int* __restrict__ cnt) {
  int t = threadIdx.x;
  int wave = t >> 6, lane = t & 63;
  {
    int row = blockIdx.x * 4 + wave;          // 0..6143
    const float* W; const float* x; const float* b; float* outp; int r;
    if (row < 3 * H) { W = Wih; x = emb + (size_t)word[0] * H; b = bih; outp = gi; r = row; }
    else             { W = Whh; x = h0;                        b = bhh; outp = gh; r = row - 3 * H; }
    const float4* Wr = (const float4*)(W + (size_t)r * H);
    const float4* xp = (const float4*)x;
    float acc = 0.f;
    #pragma unroll
    for (int u = 0; u < 4; ++u) {
      float4 w = Wr[lane + u * 64];
      float4 xx = xp[lane + u * 64];
      acc += w.x * xx.x + w.y * xx.y + w.z * xx.z + w.w * xx.w;
    }
    acc = wave_reduce_sum(acc);
    if (lane == 0) outp[r] = acc + b[r];
  }
  __threadfence();
  __shared__ int lastf;
  if (t == 0) {
    int lf = 0;
    int sub = atomicAdd(&cnt[8 + (blockIdx.x & 15)], 1);
    if (sub == 95) lf = (atomicAdd(&cnt[0], 1) == 15);   // 1536/16 = 96
    lastf = lf;
  }
  __syncthreads();
  if (!lastf) return;
  __threadfence();
  // GRU combine: 4 elems per thread
  float cacc = 0.f;
  #pragma unroll
  for (int k2 = 0; k2 < 4; ++k2) {
    int i = t + 256 * k2;
    float r = 1.f / (1.f + __expf(-(gi[i] + gh[i])));
    float z = 1.f / (1.f + __expf(-(gi[H + i] + gh[H + i])));
    float n = tanhf(gi[2 * H + i] + r * gh[2 * H + i]);
    float hn = (1.f - z) * n + z * h0[i];
    xv[i] = hn;
    out_h[i] = hn;
    v[i] = 0.f;
    cacc += battn[i] * hn;
  }
  float4 z4 = {0.f, 0.f, 0.f, 0.f};
  #pragma unroll
  for (int k2 = 0; k2 < 8; ++k2) ((float4*)ctx_p)[t + 256 * k2] = z4;  // zero 8x1024
  cacc = wave_reduce_sum(cacc);
  __shared__ float red[4];
  if (lane == 0) red[wave] = cacc;
  __syncthreads();
  if (t == 0) c0[0] = red[0] + red[1] + red[2] + red[3];
}

// ---------------- K_B: v + scores + softmax + Wout h-half ----------------
__global__ __launch_bounds__(256) void k_mid(
    const float* __restrict__ Wattn, const float* __restrict__ Wout,
    const float* __restrict__ enc, const float* __restrict__ xv,
    const float* __restrict__ c0, float* __restrict__ v,
    float* __restrict__ scores, float* __restrict__ partial,
    float* __restrict__ attn_out, int* __restrict__ cnt) {
  int t = threadIdx.x;
  int wave = t >> 6, lane = t & 63;
  int bid = blockIdx.x;
  int g = bid / 7;
  bool isS = ((bid % 7) == 0) && (g < 2048);

  // v work: claimed by arrival among {ids<256} U {scores blocks} (deadlock-free)
  if (bid < 256 || isS) {
    __shared__ int s_tk;
    if (t == 0) s_tk = atomicAdd(&cnt[1], 1);
    __syncthreads();
    int tk = s_tk;
    if (tk < 32) {
      __shared__ float sh[32];
      int j0 = tk * 32;
      if (t < 32) sh[t] = xv[j0 + t];
      __syncthreads();
      const float4* Wa = (const float4*)Wattn;
      float4 a = {0.f, 0.f, 0.f, 0.f};
      #pragma unroll 8
      for (int j = 0; j < 32; ++j) {
        float4 w = Wa[(size_t)(j0 + j) * 256 + t];
        float hj = sh[j];
        a.x += hj * w.x; a.y += hj * w.y; a.z += hj * w.z; a.w += hj * w.w;
      }
      atomicAdd(&v[4 * t + 0], a.x); atomicAdd(&v[4 * t + 1], a.y);
      atomicAdd(&v[4 * t + 2], a.z); atomicAdd(&v[4 * t + 3], a.w);
      __threadfence();
      if (t == 0) atomicAdd(&cnt[2], 1);
      __syncthreads();
    }
  }

  if (isS) {
    // wait for v complete
    if (t == 0) {
      while (__hip_atomic_load(&cnt[2], __ATOMIC_ACQUIRE, __HIP_MEMORY_SCOPE_AGENT) < 32)
        __builtin_amdgcn_s_sleep(16);
    }
    __syncthreads();
    int srow = g * 4 + wave;
    const float4* er = (const float4*)(enc + (size_t)srow * H);
    const float4* vv = (const float4*)v;
    float acc = 0.f;
    #pragma unroll
    for (int u = 0; u < 4; ++u) {
      float4 e = er[lane + u * 64];
      float4 w = vv[lane + u * 64];
      acc += e.x * w.x + e.y * w.y + e.z * w.z + e.w * w.w;
    }
    acc = wave_reduce_sum(acc);
    if (lane == 0) scores[srow] = acc + c0[0];
    __threadfence();
    __shared__ int dosm;
    if (t == 0) {
      int ds = 0;
      int sub = atomicAdd(&cnt[24 + (g & 15)], 1);
      if (sub == 127) ds = (atomicAdd(&cnt[3], 1) == 15);   // 2048/16 = 128
      dosm = ds;
    }
    __syncthreads();
    if (dosm) {
      __threadfence();
      // softmax over 8192 on 256 threads
      float vals[32];
      float mx = -1e30f;
      #pragma unroll
      for (int u2 = 0; u2 < 32; ++u2) { vals[u2] = scores[u2 * 256 + t]; mx = fmaxf(mx, vals[u2]); }
      #pragma unroll
      for (int o = 32; o > 0; o >>= 1) mx = fmaxf(mx, __shfl_down(mx, o, 64));
      __shared__ float redm[4];
      __shared__ float bc[2];
      if (lane == 0) redm[wave] = mx;
      __syncthreads();
      if (t == 0) bc[0] = fmaxf(fmaxf(redm[0], redm[1]), fmaxf(redm[2], redm[3]));
      __syncthreads();
      mx = bc[0];
      float sm = 0.f;
      #pragma unroll
      for (int u2 = 0; u2 < 32; ++u2) { vals[u2] = __expf(vals[u2] - mx); sm += vals[u2]; }
      sm = wave_reduce_sum(sm);
      if (lane == 0) redm[wave] = sm;
      __syncthreads();
      if (t == 0) bc[1] = 1.f / (redm[0] + redm[1] + redm[2] + redm[3]);
      __syncthreads();
      float inv = bc[1];
      #pragma unroll
      for (int u2 = 0; u2 < 32; ++u2) {
        float a2 = vals[u2] * inv;
        scores[u2 * 256 + t] = a2;
        attn_out[u2 * 256 + t] = a2;
      }
    }
    return;
  }

  // Wout h-half row-quad
  int nsc = bid / 7 + 1; if (nsc > 2048) nsc = 2048;
  int widx = bid - nsc;
  __shared__ float4 sx[256];
  sx[t] = ((const float4*)xv)[t];
  __syncthreads();
  int row = widx * 4 + wave;
  if (row < V) {
    const float4* wr = (const float4*)Wout + (size_t)row * 512;
    float acc = 0.f;
    #pragma unroll
    for (int u = 0; u < 4; ++u) {
      float4 w = wr[lane + u * 64];
      float4 x = sx[lane + u * 64];
      acc += w.x * x.x + w.y * x.y + w.z * x.z + w.w * x.w;
    }
    acc = wave_reduce_sum(acc);
    if (lane == 0) partial[row] = acc;
  }
}

// ---------------- K_C: ctx (work-steal) + logits ctx-half ----------------
__global__ __launch_bounds__(256) void k_ctx_logits(
    const float* __restrict__ enc, const float* __restrict__ attn,
    const float* __restrict__ Wout, const float* __restrict__ partial,
    const float* __restrict__ bout, float* __restrict__ ctx_p,
    float* __restrict__ ctx, float* __restrict__ logits, int* __restrict__ cnt) {
  int t = threadIdx.x;
  int wave = t >> 6, lane = t & 63;
  int cl = blockIdx.x & 7;
  __shared__ int s_tk;
  __shared__ int s_red;
  for (;;) {
    if (t == 0) s_tk = atomicAdd(&cnt[40 + cl], 1);
    __syncthreads();
    int tk = s_tk;
    if (tk >= 128) break;                    // 8 lanes x 128 = 1024 chunks
    int s0 = (cl + 8 * tk) * 8;              // 8 kv rows per chunk
    __shared__ float sa[8];
    if (t < 8) sa[t] = attn[s0 + t];
    __syncthreads();
    float4 a = {0.f, 0.f, 0.f, 0.f};
    #pragma unroll
    for (int j = 0; j < 8; ++j) {
      float4 e = ((const float4*)(enc + (size_t)(s0 + j) * H))[t];
      float aj = sa[j];
      a.x += aj * e.x; a.y += aj * e.y; a.z += aj * e.z; a.w += aj * e.w;
    }
    float* cp = ctx_p + cl * H;
    atomicAdd(&cp[4 * t + 0], a.x); atomicAdd(&cp[4 * t + 1], a.y);
    atomicAdd(&cp[4 * t + 2], a.z); atomicAdd(&cp[4 * t + 3], a.w);
    __threadfence();
    if (t == 0) s_red = (atomicAdd(&cnt[4], 1) == 1023);
    __syncthreads();
    if (s_red) {
      __threadfence();
      float4 sc = {0.f, 0.f, 0.f, 0.f};
      #pragma unroll
      for (int p8 = 0; p8 < 8; ++p8) {
        float4 q = ((const float4*)(ctx_p + p8 * H))[t];
        sc.x += q.x; sc.y += q.y; sc.z += q.z; sc.w += q.w;
      }
      ((float4*)ctx)[t] = sc;
      __threadfence();
      if (t == 0) __hip_atomic_store(&cnt[5], 1, __ATOMIC_RELEASE, __HIP_MEMORY_SCOPE_AGENT);
    }
    __syncthreads();   // protect sa/s_tk/s_red reuse
  }

  // logits ctx-half: prefetch W row chunk into regs, then wait for ctx
  int row = blockIdx.x * 4 + wave;
  bool ok = row < V;
  int prow = ok ? row : (V - 1);
  const float4* wr = (const float4*)Wout + (size_t)prow * 512 + 256;
  float4 w0 = wr[lane], w1 = wr[lane + 64], w2 = wr[lane + 128], w3 = wr[lane + 192];
  if (t == 0) {
    while (__hip_atomic_load(&cnt[5], __ATOMIC_ACQUIRE, __HIP_MEMORY_SCOPE_AGENT) == 0)
      __builtin_amdgcn_s_sleep(16);
  }
  __syncthreads();
  const float4* cv = (const float4*)ctx;
  float4 x0 = cv[lane], x1 = cv[lane + 64], x2 = cv[lane + 128], x3 = cv[lane + 192];
  float acc = w0.x * x0.x + w0.y * x0.y + w0.z * x0.z + w0.w * x0.w
            + w1.x * x1.x + w1.y * x1.y + w1.z * x1.z + w1.w * x1.w
            + w2.x * x2.x + w2.y * x2.y + w2.z * x2.z + w2.w * x2.w
            + w3.x * x3.x + w3.y * x3.y + w3.z * x3.z + w3.w * x3.w;
  acc = wave_reduce_sum(acc);
  if (ok && lane == 0) logits[row] = acc + partial[row] + bout[row];
}

extern "C" void kernel_launch(void* const* d_in, const int* in_sizes, int n_in,
                              void* d_out, int out_size, void* d_ws, size_t ws_size,
                              hipStream_t stream) {
  const int*   word  = (const int*)d_in[0];
  const float* h0    = (const float*)d_in[1];
  const float* enc   = (const float*)d_in[2];
  const float* emb   = (const float*)d_in[3];
  const float* Wattn = (const float*)d_in[4];
  const float* battn = (const float*)d_in[5];
  const float* Wih   = (const float*)d_in[6];
  const float* bih   = (const float*)d_in[7];
  const float* Whh   = (const float*)d_in[8];
  const float* bhh   = (const float*)d_in[9];
  const float* Wout  = (const float*)d_in[10];
  const float* bout  = (const float*)d_in[11];
  float* out = (float*)d_out;
  float* ws  = (float*)d_ws;

  int*   cnt     = (int*)d_ws;
  float* gi      = ws + 48;       // 3072
  float* gh      = ws + 3120;     // 3072
  float* xv      = ws + 6192;     // 1024 (h_new)
  float* v       = ws + 8240;     // 1024
  float* c0      = ws + 9264;     // 16
  float* scores  = ws + 9280;     // 8192 (reused as attn)
  float* partial = ws + 17472;    // 50257
  float* ctx_p   = ws + 67744;    // 8 x 1024
  float* ctx     = ws + 75936;    // 1024   (end ~ 77k floats = 308 KB)

  hipMemsetAsync((void*)cnt, 0, CNT_INTS * sizeof(int), stream);
  k_gates_gru <<<1536, 256, 0, stream>>>(Wih, Whh, bih, bhh, emb, word, h0, battn,
                                         gi, gh, xv, v, c0, ctx_p, out + V, cnt);
  k_mid       <<<2048 + NROWBLK, 256, 0, stream>>>(Wattn, Wout, enc, xv, c0, v,
                                                   scores, partial, out + V + H, cnt);
  k_ctx_logits<<<NROWBLK, 256, 0, stream>>>(enc, scores, Wout, partial, bout,
                                            ctx_p, ctx, out, cnt);
}

// Round 4
// 234.519 us; speedup vs baseline: 4.6740x; 4.6740x over previous
//
#include <hip/hip_runtime.h>
#include <math.h>

#define H 1024
#define V 50257
#define S 8192
#define NQ 12565          // ceil(V/4) row-quads of W_out
#define Q_B 7000          // quads done in k_vwout
#define Q_SC 3000         // quads done in k_scorectx
#define Q_CB (NQ - Q_B - Q_SC)   // 2565 quads in k_comb
#define CHUNKS 128        // score/context chunks
#define RPC 64            // rows per chunk (128*64 = 8192)

__device__ __forceinline__ float wave_reduce_sum(float v) {
  #pragma unroll
  for (int o = 32; o > 0; o >>= 1) v += __shfl_down(v, o, 64);
  return v;
}

// shared helper: one W_out[:,0:H] row-quad -> partial[row]
__device__ __forceinline__ void wout_h_quad(const float* __restrict__ Wout,
                                            const float* __restrict__ hnew,
                                            float* __restrict__ partial,
                                            int quad, int t) {
  __shared__ float4 sx[256];
  sx[t] = ((const float4*)hnew)[t];
  __syncthreads();
  int wave = t >> 6, lane = t & 63;
  int row = quad * 4 + wave;
  if (row < V) {
    const float4* wr = (const float4*)Wout + (size_t)row * 512;
    float acc = 0.f;
    #pragma unroll
    for (int u = 0; u < 4; ++u) {
      float4 w = wr[lane + u * 64];
      float4 x = sx[lane + u * 64];
      acc += w.x * x.x + w.y * x.y + w.z * x.z + w.w * x.w;
    }
    acc = wave_reduce_sum(acc);
    if (lane == 0) partial[row] = acc;
  }
}

// ---------------- K_A: gates + GRU (last-finisher, counter-based) ----------------
__global__ __launch_bounds__(256) void k_gates_gru(
    const float* __restrict__ Wih, const float* __restrict__ Whh,
    const float* __restrict__ bih, const float* __restrict__ bhh,
    const float* __restrict__ emb, const int* __restrict__ word,
    const float* __restrict__ h0, const float* __restrict__ battn,
    float* __restrict__ gi, float* __restrict__ gh,
    float* __restrict__ hnew, float* __restrict__ v, float* __restrict__ c0,
    float* __restrict__ out_h, int* __restrict__ cnt) {
  int t = threadIdx.x;
  int wave = t >> 6, lane = t & 63;
  {
    int row = blockIdx.x * 4 + wave;          // 0..6143
    const float* W; const float* x; const float* b; float* outp; int r;
    if (row < 3 * H) { W = Wih; x = emb + (size_t)word[0] * H; b = bih; outp = gi; r = row; }
    else             { W = Whh; x = h0;                        b = bhh; outp = gh; r = row - 3 * H; }
    const float4* Wr = (const float4*)(W + (size_t)r * H);
    const float4* xp = (const float4*)x;
    float acc = 0.f;
    #pragma unroll
    for (int u = 0; u < 4; ++u) {
      float4 w = Wr[lane + u * 64];
      float4 xx = xp[lane + u * 64];
      acc += w.x * xx.x + w.y * xx.y + w.z * xx.z + w.w * xx.w;
    }
    acc = wave_reduce_sum(acc);
    if (lane == 0) outp[r] = acc + b[r];
  }
  __threadfence();
  __shared__ int lastf;
  if (t == 0) {
    int lf = 0;
    int sub = atomicAdd(&cnt[8 + (blockIdx.x & 15)], 1);
    if (sub == 95) lf = (atomicAdd(&cnt[0], 1) == 15);   // 1536/16 = 96
    lastf = lf;
  }
  __syncthreads();
  if (!lastf) return;
  __threadfence();
  float cacc = 0.f;
  #pragma unroll
  for (int k2 = 0; k2 < 4; ++k2) {
    int i = t + 256 * k2;
    float r = 1.f / (1.f + __expf(-(gi[i] + gh[i])));
    float z = 1.f / (1.f + __expf(-(gi[H + i] + gh[H + i])));
    float n = tanhf(gi[2 * H + i] + r * gh[2 * H + i]);
    float hn = (1.f - z) * n + z * h0[i];
    hnew[i] = hn;
    out_h[i] = hn;
    v[i] = 0.f;                 // atomic target for k_vwout
    cacc += battn[i] * hn;
  }
  cacc = wave_reduce_sum(cacc);
  __shared__ float red[4];
  if (lane == 0) red[wave] = cacc;
  __syncthreads();
  if (t == 0) c0[0] = red[0] + red[1] + red[2] + red[3];
}

// ---------------- K_B: v = W_attn^T h (32 blocks) + W_out h-half quads ----------------
__global__ __launch_bounds__(256) void k_vwout(
    const float* __restrict__ Wattn, const float* __restrict__ Wout,
    const float* __restrict__ hnew, float* __restrict__ v,
    float* __restrict__ partial) {
  int t = threadIdx.x;
  if (blockIdx.x < 32) {
    __shared__ float sh[32];
    int j0 = blockIdx.x * 32;
    if (t < 32) sh[t] = hnew[j0 + t];
    __syncthreads();
    const float4* Wa = (const float4*)Wattn;
    float4 a = {0.f, 0.f, 0.f, 0.f};
    #pragma unroll 8
    for (int j = 0; j < 32; ++j) {
      float4 w = Wa[(size_t)(j0 + j) * 256 + t];
      float hj = sh[j];
      a.x += hj * w.x; a.y += hj * w.y; a.z += hj * w.z; a.w += hj * w.w;
    }
    atomicAdd(&v[4 * t + 0], a.x); atomicAdd(&v[4 * t + 1], a.y);
    atomicAdd(&v[4 * t + 2], a.z); atomicAdd(&v[4 * t + 3], a.w);
  } else {
    wout_h_quad(Wout, hnew, partial, blockIdx.x - 32, t);
  }
}

// ---------------- K_SC: fused scores + local softmax + partial context ----------------
// blocks [0,128): chunk c -> scores[64c..], m_c, S_c, cpart[c][0:1024]
// blocks [128, 128+Q_SC): W_out h-half quads Q_B + (bid-128)
__global__ __launch_bounds__(256) void k_scorectx(
    const float* __restrict__ enc, const float* __restrict__ v,
    const float* __restrict__ c0, const float* __restrict__ Wout,
    const float* __restrict__ hnew, float* __restrict__ scores,
    float* __restrict__ mvals, float* __restrict__ svals,
    float* __restrict__ cpart, float* __restrict__ partial) {
  int t = threadIdx.x;
  if (blockIdx.x >= 128) {
    wout_h_quad(Wout, hnew, partial, Q_B + (int)blockIdx.x - 128, t);
    return;
  }
  int wave = t >> 6, lane = t & 63;
  int c = blockIdx.x;
  int r0 = c * RPC;
  __shared__ float sc[RPC];
  __shared__ float wl[RPC];
  float c0v = c0[0];
  const float4* vv = (const float4*)v;
  // pass 1: 16 rows per wave
  for (int i = 0; i < 16; ++i) {
    int rl = wave * 16 + i;
    const float4* er = (const float4*)(enc + (size_t)(r0 + rl) * H);
    float acc = 0.f;
    #pragma unroll
    for (int u = 0; u < 4; ++u) {
      float4 e = er[lane + u * 64];
      float4 w = vv[lane + u * 64];
      acc += e.x * w.x + e.y * w.y + e.z * w.z + e.w * w.w;
    }
    acc = wave_reduce_sum(acc);
    if (lane == 0) {
      float s = acc + c0v;
      sc[rl] = s;
      scores[r0 + rl] = s;
    }
  }
  __syncthreads();
  // local max (redundant per thread, LDS broadcast)
  float mc = -1e30f;
  #pragma unroll 8
  for (int r = 0; r < RPC; ++r) mc = fmaxf(mc, sc[r]);
  if (t < RPC) wl[t] = __expf(sc[t] - mc);
  __syncthreads();
  if (t == 0) {
    float ssum = 0.f;
    #pragma unroll 8
    for (int r = 0; r < RPC; ++r) ssum += wl[r];
    mvals[c] = mc;
    svals[c] = ssum;
  }
  // pass 2: exp-weighted partial context (enc chunk hot in L2/L3)
  float4 a = {0.f, 0.f, 0.f, 0.f};
  #pragma unroll 4
  for (int r = 0; r < RPC; ++r) {
    float4 e = ((const float4*)(enc + (size_t)(r0 + r) * H))[t];
    float w = wl[r];
    a.x += w * e.x; a.y += w * e.y; a.z += w * e.z; a.w += w * e.w;
  }
  ((float4*)(cpart + (size_t)c * H))[t] = a;
}

// ---------------- K_comb: lse-combine -> ctx, attn; + W_out h-half quads ----------------
// blocks [0,8): ctx cols 128b..128b+127 ; blocks [8,16): attn rows 1024(b-8)..
// blocks [16, 16+Q_CB): quads Q_B + Q_SC + (bid-16)
__global__ __launch_bounds__(256) void k_comb(
    const float* __restrict__ mvals, const float* __restrict__ svals,
    const float* __restrict__ cpart, const float* __restrict__ scores,
    const float* __restrict__ Wout, const float* __restrict__ hnew,
    float* __restrict__ ctx, float* __restrict__ attn_out,
    float* __restrict__ partial) {
  int t = threadIdx.x;
  int bid = blockIdx.x;
  if (bid >= 16) {
    wout_h_quad(Wout, hnew, partial, Q_B + Q_SC + bid - 16, t);
    return;
  }
  __shared__ float wl[CHUNKS];
  float m = -1e30f;
  #pragma unroll 8
  for (int cc = 0; cc < CHUNKS; ++cc) m = fmaxf(m, mvals[cc]);
  if (t < CHUNKS) wl[t] = __expf(mvals[t] - m);
  __syncthreads();
  float den = 0.f;
  #pragma unroll 8
  for (int cc = 0; cc < CHUNKS; ++cc) den += wl[cc] * svals[cc];
  float inv = 1.f / den;
  if (bid < 8) {
    if (t < 128) {
      int k = bid * 128 + t;
      float acc = 0.f;
      #pragma unroll 4
      for (int cc = 0; cc < CHUNKS; ++cc) acc += wl[cc] * cpart[(size_t)cc * H + k];
      ctx[k] = acc * inv;
    }
  } else {
    int j = bid - 8;
    #pragma unroll
    for (int u = 0; u < 4; ++u) {
      int s = j * 1024 + t + 256 * u;
      attn_out[s] = __expf(scores[s] - m) * inv;
    }
  }
}

// ---------------- K_C: logits = partial + W_out[:,H:2H] @ ctx + b_out ----------------
__global__ __launch_bounds__(256) void k_logits(
    const float* __restrict__ Wout, const float* __restrict__ ctx,
    const float* __restrict__ partial, const float* __restrict__ bout,
    float* __restrict__ logits) {
  __shared__ float4 sx[256];
  int t = threadIdx.x;
  sx[t] = ((const float4*)ctx)[t];
  __syncthreads();
  int wave = t >> 6, lane = t & 63;
  int row = blockIdx.x * 4 + wave;
  if (row < V) {
    const float4* wr = (const float4*)Wout + (size_t)row * 512 + 256;
    float acc = 0.f;
    #pragma unroll
    for (int u = 0; u < 4; ++u) {
      float4 w = wr[lane + u * 64];
      float4 x = sx[lane + u * 64];
      acc += w.x * x.x + w.y * x.y + w.z * x.z + w.w * x.w;
    }
    acc = wave_reduce_sum(acc);
    if (lane == 0) logits[row] = acc + partial[row] + bout[row];
  }
}

extern "C" void kernel_launch(void* const* d_in, const int* in_sizes, int n_in,
                              void* d_out, int out_size, void* d_ws, size_t ws_size,
                              hipStream_t stream) {
  const int*   word  = (const int*)d_in[0];
  const float* h0    = (const float*)d_in[1];
  const float* enc   = (const float*)d_in[2];
  const float* emb   = (const float*)d_in[3];
  const float* Wattn = (const float*)d_in[4];
  const float* battn = (const float*)d_in[5];
  const float* Wih   = (const float*)d_in[6];
  const float* bih   = (const float*)d_in[7];
  const float* Whh   = (const float*)d_in[8];
  const float* bhh   = (const float*)d_in[9];
  const float* Wout  = (const float*)d_in[10];
  const float* bout  = (const float*)d_in[11];
  float* out = (float*)d_out;
  float* ws  = (float*)d_ws;

  int*   cnt     = (int*)d_ws;          // 24 ints
  float* gi      = ws + 48;             // 3072
  float* gh      = ws + 3120;           // 3072
  float* hnew    = ws + 6192;           // 1024
  float* v       = ws + 7216;           // 1024
  float* c0      = ws + 8240;           // 16
  float* scores  = ws + 8256;           // 8192
  float* partial = ws + 16448;          // 50257  (ends 66705)
  float* mvals   = ws + 66720;          // 128
  float* svals   = ws + 66848;          // 128
  float* cpart   = ws + 66976;          // 128*1024 = 131072
  float* ctx     = ws + 198048;         // 1024   (end ~199072 floats = 796 KB)

  hipMemsetAsync((void*)cnt, 0, 24 * sizeof(int), stream);
  k_gates_gru<<<1536, 256, 0, stream>>>(Wih, Whh, bih, bhh, emb, word, h0, battn,
                                        gi, gh, hnew, v, c0, out + V, cnt);
  k_vwout    <<<32 + Q_B, 256, 0, stream>>>(Wattn, Wout, hnew, v, partial);
  k_scorectx <<<128 + Q_SC, 256, 0, stream>>>(enc, v, c0, Wout, hnew,
                                              scores, mvals, svals, cpart, partial);
  k_comb     <<<16 + Q_CB, 256, 0, stream>>>(mvals, svals, cpart, scores, Wout, hnew,
                                             ctx, out + V + H, partial);
  k_logits   <<<NQ, 256, 0, stream>>>(Wout, ctx, partial, bout, out);
}

// Round 5
// 229.521 us; speedup vs baseline: 4.7758x; 1.0218x over previous
//
#include <hip/hip_runtime.h>
#include <math.h>

#define H 1024
#define V 50257
#define S 8192

// W_out[:,0:H] row partition across kernels
#define NQ_B   8000      // K_B quads: rows [0, 32000)
#define RC0    32000     // K_C quads: rows [32000, 42000)
#define NQ_C   2500
#define RSM0   42000     // K_SM 16-row blocks: rows [42000, 46096)
#define NB_SM  256
#define RCTX0  46096     // K_CTX 16-row blocks: rows [46096, 50257)
#define NB_CTX 261

__device__ __forceinline__ float wave_reduce_sum(float v) {
  #pragma unroll
  for (int o = 32; o > 0; o >>= 1) v += __shfl_down(v, o, 64);
  return v;
}

// 256-thread helper: rows row0..row0+3 of W_out[:,0:H] @ hnew -> partial
__device__ __forceinline__ void wout_h_quad(const float* __restrict__ Wout,
                                            const float* __restrict__ hnew,
                                            float* __restrict__ partial,
                                            int row0, int t) {
  __shared__ float4 sx[256];
  sx[t] = ((const float4*)hnew)[t];
  __syncthreads();
  int wave = t >> 6, lane = t & 63;
  int row = row0 + wave;
  if (row < V) {
    const float4* wr = (const float4*)Wout + (size_t)row * 512;
    float acc = 0.f;
    #pragma unroll
    for (int u = 0; u < 4; ++u) {
      float4 w = wr[lane + u * 64];
      float4 x = sx[lane + u * 64];
      acc += w.x * x.x + w.y * x.y + w.z * x.z + w.w * x.w;
    }
    acc = wave_reduce_sum(acc);
    if (lane == 0) partial[row] = acc;
  }
}

// 1024-thread helper: rows row0..row0+15
__device__ __forceinline__ void wout_h_16(const float* __restrict__ Wout,
                                          const float* __restrict__ hnew,
                                          float* __restrict__ partial,
                                          int row0, int t) {
  __shared__ float4 sx[256];
  if (t < 256) sx[t] = ((const float4*)hnew)[t];
  __syncthreads();
  int wave = t >> 6, lane = t & 63;   // 16 waves
  int row = row0 + wave;
  if (row < V) {
    const float4* wr = (const float4*)Wout + (size_t)row * 512;
    float acc = 0.f;
    #pragma unroll
    for (int u = 0; u < 4; ++u) {
      float4 w = wr[lane + u * 64];
      float4 x = sx[lane + u * 64];
      acc += w.x * x.x + w.y * x.y + w.z * x.z + w.w * x.w;
    }
    acc = wave_reduce_sum(acc);
    if (lane == 0) partial[row] = acc;
  }
}

// ---------------- K_A: gates + GRU (last-finisher, proven R3/R4) ----------------
__global__ __launch_bounds__(256) void k_gates_gru(
    const float* __restrict__ Wih, const float* __restrict__ Whh,
    const float* __restrict__ bih, const float* __restrict__ bhh,
    const float* __restrict__ emb, const int* __restrict__ word,
    const float* __restrict__ h0, const float* __restrict__ battn,
    float* __restrict__ gi, float* __restrict__ gh,
    float* __restrict__ hnew, float* __restrict__ v, float* __restrict__ ctx,
    float* __restrict__ c0, float* __restrict__ out_h, int* __restrict__ cnt) {
  int t = threadIdx.x;
  int wave = t >> 6, lane = t & 63;
  {
    int row = blockIdx.x * 4 + wave;          // 0..6143
    const float* W; const float* x; const float* b; float* outp; int r;
    if (row < 3 * H) { W = Wih; x = emb + (size_t)word[0] * H; b = bih; outp = gi; r = row; }
    else             { W = Whh; x = h0;                        b = bhh; outp = gh; r = row - 3 * H; }
    const float4* Wr = (const float4*)(W + (size_t)r * H);
    const float4* xp = (const float4*)x;
    float acc = 0.f;
    #pragma unroll
    for (int u = 0; u < 4; ++u) {
      float4 w = Wr[lane + u * 64];
      float4 xx = xp[lane + u * 64];
      acc += w.x * xx.x + w.y * xx.y + w.z * xx.z + w.w * xx.w;
    }
    acc = wave_reduce_sum(acc);
    if (lane == 0) outp[r] = acc + b[r];
  }
  __threadfence();
  __shared__ int lastf;
  if (t == 0) {
    int lf = 0;
    int sub = atomicAdd(&cnt[8 + (blockIdx.x & 15)], 1);
    if (sub == 95) lf = (atomicAdd(&cnt[0], 1) == 15);   // 1536/16 = 96
    lastf = lf;
  }
  __syncthreads();
  if (!lastf) return;
  __threadfence();
  float cacc = 0.f;
  #pragma unroll
  for (int k2 = 0; k2 < 4; ++k2) {
    int i = t + 256 * k2;
    float r = 1.f / (1.f + __expf(-(gi[i] + gh[i])));
    float z = 1.f / (1.f + __expf(-(gi[H + i] + gh[H + i])));
    float n = tanhf(gi[2 * H + i] + r * gh[2 * H + i]);
    float hn = (1.f - z) * n + z * h0[i];
    hnew[i] = hn;
    out_h[i] = hn;
    v[i] = 0.f;                 // atomic target for K_B
    ctx[i] = 0.f;               // atomic target for K_CTX
    cacc += battn[i] * hn;
  }
  cacc = wave_reduce_sum(cacc);
  __shared__ float red[4];
  if (lane == 0) red[wave] = cacc;
  __syncthreads();
  if (t == 0) c0[0] = red[0] + red[1] + red[2] + red[3];
}

// ---------------- K_B: 32 v-blocks + quads rows [0, 32000) ----------------
__global__ __launch_bounds__(256) void k_b(
    const float* __restrict__ Wattn, const float* __restrict__ Wout,
    const float* __restrict__ hnew, float* __restrict__ v,
    float* __restrict__ partial) {
  int t = threadIdx.x;
  if (blockIdx.x < 32) {
    __shared__ float sh[32];
    int j0 = blockIdx.x * 32;
    if (t < 32) sh[t] = hnew[j0 + t];
    __syncthreads();
    const float4* Wa = (const float4*)Wattn;
    float4 a = {0.f, 0.f, 0.f, 0.f};
    #pragma unroll 8
    for (int j = 0; j < 32; ++j) {
      float4 w = Wa[(size_t)(j0 + j) * 256 + t];
      float hj = sh[j];
      a.x += hj * w.x; a.y += hj * w.y; a.z += hj * w.z; a.w += hj * w.w;
    }
    atomicAdd(&v[4 * t + 0], a.x); atomicAdd(&v[4 * t + 1], a.y);
    atomicAdd(&v[4 * t + 2], a.z); atomicAdd(&v[4 * t + 3], a.w);
  } else {
    wout_h_quad(Wout, hnew, partial, (blockIdx.x - 32) * 4, t);
  }
}

// ---------------- K_C: 2048 thin score blocks + quads rows [32000, 42000) ----------------
__global__ __launch_bounds__(256) void k_c(
    const float* __restrict__ enc, const float* __restrict__ v,
    const float* __restrict__ c0, const float* __restrict__ Wout,
    const float* __restrict__ hnew, float* __restrict__ scores,
    float* __restrict__ partial) {
  int t = threadIdx.x;
  if (blockIdx.x < 2048) {
    int wave = t >> 6, lane = t & 63;
    int srow = blockIdx.x * 4 + wave;
    const float4* er = (const float4*)(enc + (size_t)srow * H);
    const float4* vv = (const float4*)v;
    float acc = 0.f;
    #pragma unroll
    for (int u = 0; u < 4; ++u) {
      float4 e = er[lane + u * 64];
      float4 w = vv[lane + u * 64];
      acc += e.x * w.x + e.y * w.y + e.z * w.z + e.w * w.w;
    }
    acc = wave_reduce_sum(acc);
    if (lane == 0) scores[srow] = acc + c0[0];
  } else {
    wout_h_quad(Wout, hnew, partial, RC0 + (blockIdx.x - 2048) * 4, t);
  }
}

// ---------------- K_SM: softmax (block 0, R2-proven body) + 16-row quads ----------------
__global__ __launch_bounds__(1024) void k_sm(
    float* __restrict__ scores, float* __restrict__ attn_out,
    const float* __restrict__ Wout, const float* __restrict__ hnew,
    float* __restrict__ partial) {
  int t = threadIdx.x;
  if (blockIdx.x != 0) {
    wout_h_16(Wout, hnew, partial, RSM0 + ((int)blockIdx.x - 1) * 16, t);
    return;
  }
  __shared__ float red[16];
  __shared__ float bc[2];
  float vals[8];
  float m = -1e30f;
  #pragma unroll
  for (int u = 0; u < 8; ++u) { vals[u] = scores[u * 1024 + t]; m = fmaxf(m, vals[u]); }
  #pragma unroll
  for (int o = 32; o > 0; o >>= 1) m = fmaxf(m, __shfl_down(m, o, 64));
  if ((t & 63) == 0) red[t >> 6] = m;
  __syncthreads();
  if (t == 0) {
    float mm = red[0];
    #pragma unroll
    for (int k = 1; k < 16; ++k) mm = fmaxf(mm, red[k]);
    bc[0] = mm;
  }
  __syncthreads();
  m = bc[0];
  float s = 0.f;
  #pragma unroll
  for (int u = 0; u < 8; ++u) { vals[u] = __expf(vals[u] - m); s += vals[u]; }
  s = wave_reduce_sum(s);
  if ((t & 63) == 0) red[t >> 6] = s;
  __syncthreads();
  if (t == 0) {
    float ss = 0.f;
    #pragma unroll
    for (int k = 0; k < 16; ++k) ss += red[k];
    bc[1] = 1.f / ss;
  }
  __syncthreads();
  float inv = bc[1];
  #pragma unroll
  for (int u = 0; u < 8; ++u) {
    float a = vals[u] * inv;
    scores[u * 1024 + t] = a;
    attn_out[u * 1024 + t] = a;
  }
}

// ---------------- K_CTX: 256 ctx blocks (R2-proven) + 16-row quads ----------------
__global__ __launch_bounds__(1024) void k_ctx2(
    const float* __restrict__ enc, const float* __restrict__ attn,
    float* __restrict__ ctx, const float* __restrict__ Wout,
    const float* __restrict__ hnew, float* __restrict__ partial) {
  int t = threadIdx.x;
  if (blockIdx.x >= 256) {
    wout_h_16(Wout, hnew, partial, RCTX0 + ((int)blockIdx.x - 256) * 16, t);
    return;
  }
  __shared__ float sa[32];
  int s0 = blockIdx.x * 32;
  if (t < 32) sa[t] = attn[s0 + t];
  __syncthreads();
  float acc = 0.f;
  #pragma unroll 8
  for (int j = 0; j < 32; ++j)
    acc += sa[j] * enc[(size_t)(s0 + j) * H + t];
  atomicAdd(&ctx[t], acc);
}

// ---------------- K_LOG: logits = partial + W_out[:,H:2H] @ ctx + b_out ----------------
__global__ __launch_bounds__(256) void k_logits(
    const float* __restrict__ Wout, const float* __restrict__ ctx,
    const float* __restrict__ partial, const float* __restrict__ bout,
    float* __restrict__ logits) {
  __shared__ float4 sx[256];
  int t = threadIdx.x;
  sx[t] = ((const float4*)ctx)[t];
  __syncthreads();
  int wave = t >> 6, lane = t & 63;
  int row = blockIdx.x * 4 + wave;
  if (row < V) {
    const float4* wr = (const float4*)Wout + (size_t)row * 512 + 256;
    float acc = 0.f;
    #pragma unroll
    for (int u = 0; u < 4; ++u) {
      float4 w = wr[lane + u * 64];
      float4 x = sx[lane + u * 64];
      acc += w.x * x.x + w.y * x.y + w.z * x.z + w.w * x.w;
    }
    acc = wave_reduce_sum(acc);
    if (lane == 0) logits[row] = acc + partial[row] + bout[row];
  }
}

extern "C" void kernel_launch(void* const* d_in, const int* in_sizes, int n_in,
                              void* d_out, int out_size, void* d_ws, size_t ws_size,
                              hipStream_t stream) {
  const int*   word  = (const int*)d_in[0];
  const float* h0    = (const float*)d_in[1];
  const float* enc   = (const float*)d_in[2];
  const float* emb   = (const float*)d_in[3];
  const float* Wattn = (const float*)d_in[4];
  const float* battn = (const float*)d_in[5];
  const float* Wih   = (const float*)d_in[6];
  const float* bih   = (const float*)d_in[7];
  const float* Whh   = (const float*)d_in[8];
  const float* bhh   = (const float*)d_in[9];
  const float* Wout  = (const float*)d_in[10];
  const float* bout  = (const float*)d_in[11];
  float* out = (float*)d_out;
  float* ws  = (float*)d_ws;

  int*   cnt     = (int*)d_ws;          // 24 ints used (zeroed each replay)
  float* gi      = ws + 48;             // 3072
  float* gh      = ws + 3120;           // 3072
  float* hnew    = ws + 6192;           // 1024
  float* v       = ws + 7216;           // 1024
  float* c0      = ws + 8240;           // 16
  float* scores  = ws + 8256;           // 8192 (reused as attn)
  float* ctx     = ws + 16448;          // 1024
  float* partial = ws + 17472;          // 50257 (end ~67729 floats = 271 KB)

  hipMemsetAsync((void*)cnt, 0, 24 * sizeof(int), stream);
  k_gates_gru<<<1536, 256, 0, stream>>>(Wih, Whh, bih, bhh, emb, word, h0, battn,
                                        gi, gh, hnew, v, ctx, c0, out + V, cnt);
  k_b        <<<32 + NQ_B, 256, 0, stream>>>(Wattn, Wout, hnew, v, partial);
  k_c        <<<2048 + NQ_C, 256, 0, stream>>>(enc, v, c0, Wout, hnew, scores, partial);
  k_sm       <<<1 + NB_SM, 1024, 0, stream>>>(scores, out + V + H, Wout, hnew, partial);
  k_ctx2     <<<256 + NB_CTX, 1024, 0, stream>>>(enc, scores, ctx, Wout, hnew, partial);
  k_logits   <<<(V + 3) / 4, 256, 0, stream>>>(Wout, ctx, partial, bout, out);
}

// Round 6
// 105.049 us; speedup vs baseline: 10.4347x; 2.1849x over previous
//
#include <hip/hip_runtime.h>
#include <math.h>

#define H 1024
#define V 50257
#define S 8192

// W_out[:,0:H] row partition across kernels (rows of the h-half stream)
#define NQ_B   8000      // k_b quads: rows [0, 32000)
#define RC0    32000     // k_c quads: rows [32000, 42000)
#define NQ_C   2500
#define RSM0   42000     // k_sm 16-row blocks: rows [42000, 46096)
#define NB_SM  256
#define RCTX0  46096     // k_ctx2 16-row blocks: rows [46096, 50257)
#define NB_CTX 261       // 261*16 = 4176 >= 4161

__device__ __forceinline__ float wave_reduce_sum(float v) {
  #pragma unroll
  for (int o = 32; o > 0; o >>= 1) v += __shfl_down(v, o, 64);
  return v;
}

// 256-thread helper: rows row0..row0+3 of W_out[:,0:H] @ hnew -> partial
__device__ __forceinline__ void wout_h_quad(const float* __restrict__ Wout,
                                            const float* __restrict__ hnew,
                                            float* __restrict__ partial,
                                            int row0, int t) {
  __shared__ float4 sx[256];
  sx[t] = ((const float4*)hnew)[t];
  __syncthreads();
  int wave = t >> 6, lane = t & 63;
  int row = row0 + wave;
  if (row < V) {
    const float4* wr = (const float4*)Wout + (size_t)row * 512;
    float acc = 0.f;
    #pragma unroll
    for (int u = 0; u < 4; ++u) {
      float4 w = wr[lane + u * 64];
      float4 x = sx[lane + u * 64];
      acc += w.x * x.x + w.y * x.y + w.z * x.z + w.w * x.w;
    }
    acc = wave_reduce_sum(acc);
    if (lane == 0) partial[row] = acc;
  }
}

// 1024-thread helper: rows row0..row0+15
__device__ __forceinline__ void wout_h_16(const float* __restrict__ Wout,
                                          const float* __restrict__ hnew,
                                          float* __restrict__ partial,
                                          int row0, int t) {
  __shared__ float4 sx[256];
  if (t < 256) sx[t] = ((const float4*)hnew)[t];
  __syncthreads();
  int wave = t >> 6, lane = t & 63;   // 16 waves
  int row = row0 + wave;
  if (row < V) {
    const float4* wr = (const float4*)Wout + (size_t)row * 512;
    float acc = 0.f;
    #pragma unroll
    for (int u = 0; u < 4; ++u) {
      float4 w = wr[lane + u * 64];
      float4 x = sx[lane + u * 64];
      acc += w.x * x.x + w.y * x.y + w.z * x.z + w.w * x.w;
    }
    acc = wave_reduce_sum(acc);
    if (lane == 0) partial[row] = acc;
  }
}

// K1: gi = W_ih @ x + b_ih ; gh = W_hh @ h + b_hh   (R2-proven, no fences)
__global__ __launch_bounds__(256) void k_gates(
    const float* __restrict__ Wih, const float* __restrict__ Whh,
    const float* __restrict__ bih, const float* __restrict__ bhh,
    const float* __restrict__ emb, const int* __restrict__ word,
    const float* __restrict__ h0, float* __restrict__ gi, float* __restrict__ gh) {
  int wave = threadIdx.x >> 6, lane = threadIdx.x & 63;
  int row = blockIdx.x * 4 + wave;          // 0..6143
  const float* W; const float* x; const float* b; float* out; int r;
  if (row < 3 * H) { W = Wih; x = emb + (size_t)word[0] * H; b = bih; out = gi; r = row; }
  else             { W = Whh; x = h0;                        b = bhh; out = gh; r = row - 3 * H; }
  const float4* Wr = (const float4*)(W + (size_t)r * H);
  const float4* xv = (const float4*)x;
  float acc = 0.f;
  #pragma unroll
  for (int u = 0; u < 4; ++u) {
    float4 w = Wr[lane + u * 64];
    float4 xx = xv[lane + u * 64];
    acc += w.x * xx.x + w.y * xx.y + w.z * xx.z + w.w * xx.w;
  }
  acc = wave_reduce_sum(acc);
  if (lane == 0) out[r] = acc + b[r];
}

// K2: GRU combine -> h_new, c0 = dot(b_attn,h_new); zero v, ctx (R2-proven)
__global__ __launch_bounds__(1024) void k_gru(
    const float* __restrict__ gi, const float* __restrict__ gh,
    const float* __restrict__ h0, const float* __restrict__ battn,
    float* __restrict__ hnew, float* __restrict__ v, float* __restrict__ ctx,
    float* __restrict__ c0, float* __restrict__ out_h) {
  __shared__ float red[16];
  int i = threadIdx.x;
  float r = 1.f / (1.f + __expf(-(gi[i] + gh[i])));
  float z = 1.f / (1.f + __expf(-(gi[H + i] + gh[H + i])));
  float n = tanhf(gi[2 * H + i] + r * gh[2 * H + i]);
  float hn = (1.f - z) * n + z * h0[i];
  hnew[i] = hn;
  out_h[i] = hn;
  v[i] = 0.f;          // atomic target for k_b
  ctx[i] = 0.f;        // atomic target for k_ctx2
  float p = battn[i] * hn;
  float w = wave_reduce_sum(p);
  if ((i & 63) == 0) red[i >> 6] = w;
  __syncthreads();
  if (i == 0) {
    float s = 0.f;
    #pragma unroll
    for (int k = 0; k < 16; ++k) s += red[k];
    c0[0] = s;
  }
}

// K3: 32 v-blocks (W_attn^T h, atomicAdd) + W_out h-half quads rows [0, 32000)
__global__ __launch_bounds__(256) void k_b(
    const float* __restrict__ Wattn, const float* __restrict__ Wout,
    const float* __restrict__ hnew, float* __restrict__ v,
    float* __restrict__ partial) {
  int t = threadIdx.x;
  if (blockIdx.x < 32) {
    __shared__ float sh[32];
    int j0 = blockIdx.x * 32;
    if (t < 32) sh[t] = hnew[j0 + t];
    __syncthreads();
    const float4* Wa = (const float4*)Wattn;
    float4 a = {0.f, 0.f, 0.f, 0.f};
    #pragma unroll 8
    for (int j = 0; j < 32; ++j) {
      float4 w = Wa[(size_t)(j0 + j) * 256 + t];
      float hj = sh[j];
      a.x += hj * w.x; a.y += hj * w.y; a.z += hj * w.z; a.w += hj * w.w;
    }
    atomicAdd(&v[4 * t + 0], a.x); atomicAdd(&v[4 * t + 1], a.y);
    atomicAdd(&v[4 * t + 2], a.z); atomicAdd(&v[4 * t + 3], a.w);
  } else {
    wout_h_quad(Wout, hnew, partial, (blockIdx.x - 32) * 4, t);
  }
}

// K4: 2048 thin score blocks + quads rows [32000, 42000)
__global__ __launch_bounds__(256) void k_c(
    const float* __restrict__ enc, const float* __restrict__ v,
    const float* __restrict__ c0, const float* __restrict__ Wout,
    const float* __restrict__ hnew, float* __restrict__ scores,
    float* __restrict__ partial) {
  int t = threadIdx.x;
  if (blockIdx.x < 2048) {
    int wave = t >> 6, lane = t & 63;
    int srow = blockIdx.x * 4 + wave;
    const float4* er = (const float4*)(enc + (size_t)srow * H);
    const float4* vv = (const float4*)v;
    float acc = 0.f;
    #pragma unroll
    for (int u = 0; u < 4; ++u) {
      float4 e = er[lane + u * 64];
      float4 w = vv[lane + u * 64];
      acc += e.x * w.x + e.y * w.y + e.z * w.z + e.w * w.w;
    }
    acc = wave_reduce_sum(acc);
    if (lane == 0) scores[srow] = acc + c0[0];
  } else {
    wout_h_quad(Wout, hnew, partial, RC0 + (blockIdx.x - 2048) * 4, t);
  }
}

// K5: softmax (block 0, R2-proven body) + 16-row quads rows [42000, 46096)
__global__ __launch_bounds__(1024) void k_sm(
    float* __restrict__ scores, float* __restrict__ attn_out,
    const float* __restrict__ Wout, const float* __restrict__ hnew,
    float* __restrict__ partial) {
  int t = threadIdx.x;
  if (blockIdx.x != 0) {
    wout_h_16(Wout, hnew, partial, RSM0 + ((int)blockIdx.x - 1) * 16, t);
    return;
  }
  __shared__ float red[16];
  __shared__ float bc[2];
  float vals[8];
  float m = -1e30f;
  #pragma unroll
  for (int u = 0; u < 8; ++u) { vals[u] = scores[u * 1024 + t]; m = fmaxf(m, vals[u]); }
  #pragma unroll
  for (int o = 32; o > 0; o >>= 1) m = fmaxf(m, __shfl_down(m, o, 64));
  if ((t & 63) == 0) red[t >> 6] = m;
  __syncthreads();
  if (t == 0) {
    float mm = red[0];
    #pragma unroll
    for (int k = 1; k < 16; ++k) mm = fmaxf(mm, red[k]);
    bc[0] = mm;
  }
  __syncthreads();
  m = bc[0];
  float s = 0.f;
  #pragma unroll
  for (int u = 0; u < 8; ++u) { vals[u] = __expf(vals[u] - m); s += vals[u]; }
  s = wave_reduce_sum(s);
  if ((t & 63) == 0) red[t >> 6] = s;
  __syncthreads();
  if (t == 0) {
    float ss = 0.f;
    #pragma unroll
    for (int k = 0; k < 16; ++k) ss += red[k];
    bc[1] = 1.f / ss;
  }
  __syncthreads();
  float inv = bc[1];
  #pragma unroll
  for (int u = 0; u < 8; ++u) {
    float a = vals[u] * inv;
    scores[u * 1024 + t] = a;
    attn_out[u * 1024 + t] = a;
  }
}

// K6: 256 ctx blocks (R2-proven, atomicAdd) + 16-row quads rows [46096, 50257)
__global__ __launch_bounds__(1024) void k_ctx2(
    const float* __restrict__ enc, const float* __restrict__ attn,
    float* __restrict__ ctx, const float* __restrict__ Wout,
    const float* __restrict__ hnew, float* __restrict__ partial) {
  int t = threadIdx.x;
  if (blockIdx.x >= 256) {
    wout_h_16(Wout, hnew, partial, RCTX0 + ((int)blockIdx.x - 256) * 16, t);
    return;
  }
  __shared__ float sa[32];
  int s0 = blockIdx.x * 32;
  if (t < 32) sa[t] = attn[s0 + t];
  __syncthreads();
  float acc = 0.f;
  #pragma unroll 8
  for (int j = 0; j < 32; ++j)
    acc += sa[j] * enc[(size_t)(s0 + j) * H + t];
  atomicAdd(&ctx[t], acc);
}

// K7: logits = partial + W_out[:,H:2H] @ ctx + b_out
__global__ __launch_bounds__(256) void k_logits(
    const float* __restrict__ Wout, const float* __restrict__ ctx,
    const float* __restrict__ partial, const float* __restrict__ bout,
    float* __restrict__ logits) {
  __shared__ float4 sx[256];
  int t = threadIdx.x;
  sx[t] = ((const float4*)ctx)[t];
  __syncthreads();
  int wave = t >> 6, lane = t & 63;
  int row = blockIdx.x * 4 + wave;
  if (row < V) {
    const float4* wr = (const float4*)Wout + (size_t)row * 512 + 256;
    float acc = 0.f;
    #pragma unroll
    for (int u = 0; u < 4; ++u) {
      float4 w = wr[lane + u * 64];
      float4 x = sx[lane + u * 64];
      acc += w.x * x.x + w.y * x.y + w.z * x.z + w.w * x.w;
    }
    acc = wave_reduce_sum(acc);
    if (lane == 0) logits[row] = acc + partial[row] + bout[row];
  }
}

extern "C" void kernel_launch(void* const* d_in, const int* in_sizes, int n_in,
                              void* d_out, int out_size, void* d_ws, size_t ws_size,
                              hipStream_t stream) {
  const int*   word  = (const int*)d_in[0];
  const float* h0    = (const float*)d_in[1];
  const float* enc   = (const float*)d_in[2];
  const float* emb   = (const float*)d_in[3];
  const float* Wattn = (const float*)d_in[4];
  const float* battn = (const float*)d_in[5];
  const float* Wih   = (const float*)d_in[6];
  const float* bih   = (const float*)d_in[7];
  const float* Whh   = (const float*)d_in[8];
  const float* bhh   = (const float*)d_in[9];
  const float* Wout  = (const float*)d_in[10];
  const float* bout  = (const float*)d_in[11];
  float* out = (float*)d_out;
  float* ws  = (float*)d_ws;

  float* gi      = ws;                  // 3072
  float* gh      = ws + 3072;           // 3072
  float* hnew    = ws + 6144;           // 1024
  float* v       = ws + 7168;           // 1024
  float* c0      = ws + 8192;           // 16
  float* scores  = ws + 8208;           // 8192 (reused as attn)
  float* ctx     = ws + 16400;          // 1024
  float* partial = ws + 17424;          // 50257 (end ~67681 floats = 271 KB)

  k_gates <<<1536, 256, 0, stream>>>(Wih, Whh, bih, bhh, emb, word, h0, gi, gh);
  k_gru   <<<1, 1024, 0, stream>>>(gi, gh, h0, battn, hnew, v, ctx, c0, out + V);
  k_b     <<<32 + NQ_B, 256, 0, stream>>>(Wattn, Wout, hnew, v, partial);
  k_c     <<<2048 + NQ_C, 256, 0, stream>>>(enc, v, c0, Wout, hnew, scores, partial);
  k_sm    <<<1 + NB_SM, 1024, 0, stream>>>(scores, out + V + H, Wout, hnew, partial);
  k_ctx2  <<<256 + NB_CTX, 1024, 0, stream>>>(enc, scores, ctx, Wout, hnew, partial);
  k_logits<<<(V + 3) / 4, 256, 0, stream>>>(Wout, ctx, partial, bout, out);
}

// Round 7
// 102.718 us; speedup vs baseline: 10.6715x; 1.0227x over previous
//
#include <hip/hip_runtime.h>
#include <math.h>

#define H 1024
#define V 50257
#define S 8192

// W_out[:,0:H] h-half row partition
#define Q_B   6000      // k_b quads: rows [0, 24000)
#define RC0   24000     // k_c quads: rows [24000, 38000)
#define Q_C   3500
#define RX0   38000     // k_ctx2 16-row blocks: rows [38000, 50257)
#define NB_X  767       // 767*16 = 12272 >= 12257

__device__ __forceinline__ float wave_reduce_sum(float v) {
  #pragma unroll
  for (int o = 32; o > 0; o >>= 1) v += __shfl_down(v, o, 64);
  return v;
}

__device__ __forceinline__ float sigmf(float x) { return 1.f / (1.f + __expf(-x)); }
// tanh(x) = 1 - 2/(e^2x + 1): safe at both saturations (inf -> 1, 0 -> -1)
__device__ __forceinline__ float tanhfast(float x) { return 1.f - 2.f / (__expf(2.f * x) + 1.f); }
__device__ __forceinline__ float gru_one(float gir, float giz, float gin,
                                         float ghr, float ghz, float ghn, float h) {
  float r = sigmf(gir + ghr);
  float z = sigmf(giz + ghz);
  float n = tanhfast(gin + r * ghn);
  return (1.f - z) * n + z * h;
}

// compute hnew[4t..4t+3] from gi/gh/h0 (all float4, coalesced, L2-hot)
__device__ __forceinline__ float4 gru_vec4(const float* __restrict__ gi,
                                           const float* __restrict__ gh,
                                           const float* __restrict__ h0, int t) {
  const float4* gi4 = (const float4*)gi;
  const float4* gh4 = (const float4*)gh;
  const float4* h04 = (const float4*)h0;
  float4 a = gi4[t], b = gi4[256 + t], c = gi4[512 + t];
  float4 d = gh4[t], e = gh4[256 + t], f = gh4[512 + t];
  float4 h = h04[t];
  float4 o;
  o.x = gru_one(a.x, b.x, c.x, d.x, e.x, f.x, h.x);
  o.y = gru_one(a.y, b.y, c.y, d.y, e.y, f.y, h.y);
  o.z = gru_one(a.z, b.z, c.z, d.z, e.z, f.z, h.z);
  o.w = gru_one(a.w, b.w, c.w, d.w, e.w, f.w, h.w);
  return o;
}

// 256-thread: rows row0..row0+3 of W_out[:,0:H] @ sx -> partial (sx prefilled)
__device__ __forceinline__ void wout_quad_dot(const float* __restrict__ Wout,
                                              const float4* sx,
                                              float* __restrict__ partial,
                                              int row0, int t) {
  int wave = t >> 6, lane = t & 63;
  int row = row0 + wave;
  if (row < V) {
    const float4* wr = (const float4*)Wout + (size_t)row * 512;
    float acc = 0.f;
    #pragma unroll
    for (int u = 0; u < 4; ++u) {
      float4 w = wr[lane + u * 64];
      float4 x = sx[lane + u * 64];
      acc += w.x * x.x + w.y * x.y + w.z * x.z + w.w * x.w;
    }
    acc = wave_reduce_sum(acc);
    if (lane == 0) partial[row] = acc;
  }
}

// 1024-thread helper: rows row0..row0+15, hnew from ws
__device__ __forceinline__ void wout_h_16(const float* __restrict__ Wout,
                                          const float* __restrict__ hnew,
                                          float* __restrict__ partial,
                                          int row0, int t) {
  __shared__ float4 sx[256];
  if (t < 256) sx[t] = ((const float4*)hnew)[t];
  __syncthreads();
  int wave = t >> 6, lane = t & 63;   // 16 waves
  int row = row0 + wave;
  if (row < V) {
    const float4* wr = (const float4*)Wout + (size_t)row * 512;
    float acc = 0.f;
    #pragma unroll
    for (int u = 0; u < 4; ++u) {
      float4 w = wr[lane + u * 64];
      float4 x = sx[lane + u * 64];
      acc += w.x * x.x + w.y * x.y + w.z * x.z + w.w * x.w;
    }
    acc = wave_reduce_sum(acc);
    if (lane == 0) partial[row] = acc;
  }
}

// K1: gates; block 0 also zeroes the atomic targets v, ctx
__global__ __launch_bounds__(256) void k_gates(
    const float* __restrict__ Wih, const float* __restrict__ Whh,
    const float* __restrict__ bih, const float* __restrict__ bhh,
    const float* __restrict__ emb, const int* __restrict__ word,
    const float* __restrict__ h0, float* __restrict__ gi, float* __restrict__ gh,
    float* __restrict__ v, float* __restrict__ ctx) {
  int t = threadIdx.x;
  int wave = t >> 6, lane = t & 63;
  if (blockIdx.x == 0) {
    float4 z4 = {0.f, 0.f, 0.f, 0.f};
    ((float4*)v)[t] = z4;
    ((float4*)ctx)[t] = z4;
  }
  int row = blockIdx.x * 4 + wave;          // 0..6143
  const float* W; const float* x; const float* b; float* out; int r;
  if (row < 3 * H) { W = Wih; x = emb + (size_t)word[0] * H; b = bih; out = gi; r = row; }
  else             { W = Whh; x = h0;                        b = bhh; out = gh; r = row - 3 * H; }
  const float4* Wr = (const float4*)(W + (size_t)r * H);
  const float4* xv = (const float4*)x;
  float acc = 0.f;
  #pragma unroll
  for (int u = 0; u < 4; ++u) {
    float4 w = Wr[lane + u * 64];
    float4 xx = xv[lane + u * 64];
    acc += w.x * xx.x + w.y * xx.y + w.z * xx.z + w.w * xx.w;
  }
  acc = wave_reduce_sum(acc);
  if (lane == 0) out[r] = acc + b[r];
}

// K2 (= old k_b + k_gru): redundant GRU per block.
//  blocks 0..31: v-chunk (W_attn^T h, atomicAdd); block 0 also writes hnew/out_h/c0
//  blocks 32.. : W_out h-half quads rows [0, 24000)
__global__ __launch_bounds__(256) void k_b(
    const float* __restrict__ Wattn, const float* __restrict__ Wout,
    const float* __restrict__ gi, const float* __restrict__ gh,
    const float* __restrict__ h0, const float* __restrict__ battn,
    float* __restrict__ hnew, float* __restrict__ out_h, float* __restrict__ c0,
    float* __restrict__ v, float* __restrict__ partial) {
  int t = threadIdx.x;
  int wave = t >> 6, lane = t & 63;
  if (blockIdx.x < 32) {
    __shared__ float sh[32];
    __shared__ float red[4];
    int j0 = blockIdx.x * 32;
    if (t < 32) {
      int i = j0 + t;
      sh[t] = gru_one(gi[i], gi[H + i], gi[2 * H + i],
                      gh[i], gh[H + i], gh[2 * H + i], h0[i]);
    }
    if (blockIdx.x == 0) {
      float4 o = gru_vec4(gi, gh, h0, t);
      ((float4*)hnew)[t] = o;
      ((float4*)out_h)[t] = o;
      float4 bv = ((const float4*)battn)[t];
      float p = bv.x * o.x + bv.y * o.y + bv.z * o.z + bv.w * o.w;
      p = wave_reduce_sum(p);
      if (lane == 0) red[wave] = p;
      __syncthreads();
      if (t == 0) c0[0] = red[0] + red[1] + red[2] + red[3];
    }
    __syncthreads();
    const float4* Wa = (const float4*)Wattn;
    float4 a = {0.f, 0.f, 0.f, 0.f};
    #pragma unroll 8
    for (int j = 0; j < 32; ++j) {
      float4 w = Wa[(size_t)(j0 + j) * 256 + t];
      float hj = sh[j];
      a.x += hj * w.x; a.y += hj * w.y; a.z += hj * w.z; a.w += hj * w.w;
    }
    atomicAdd(&v[4 * t + 0], a.x); atomicAdd(&v[4 * t + 1], a.y);
    atomicAdd(&v[4 * t + 2], a.z); atomicAdd(&v[4 * t + 3], a.w);
  } else {
    __shared__ float4 sx[256];
    sx[t] = gru_vec4(gi, gh, h0, t);   // redundant GRU, L2-hot inputs
    __syncthreads();
    wout_quad_dot(Wout, sx, partial, (blockIdx.x - 32) * 4, t);
  }
}

// K3: 2048 thin score blocks + quads rows [24000, 38000)
__global__ __launch_bounds__(256) void k_c(
    const float* __restrict__ enc, const float* __restrict__ v,
    const float* __restrict__ c0, const float* __restrict__ Wout,
    const float* __restrict__ hnew, float* __restrict__ scores,
    float* __restrict__ partial) {
  int t = threadIdx.x;
  if (blockIdx.x < 2048) {
    int wave = t >> 6, lane = t & 63;
    int srow = blockIdx.x * 4 + wave;
    const float4* er = (const float4*)(enc + (size_t)srow * H);
    const float4* vv = (const float4*)v;
    float acc = 0.f;
    #pragma unroll
    for (int u = 0; u < 4; ++u) {
      float4 e = er[lane + u * 64];
      float4 w = vv[lane + u * 64];
      acc += e.x * w.x + e.y * w.y + e.z * w.z + e.w * w.w;
    }
    acc = wave_reduce_sum(acc);
    if (lane == 0) scores[srow] = acc + c0[0];
  } else {
    __shared__ float4 sx[256];
    sx[t] = ((const float4*)hnew)[t];
    __syncthreads();
    wout_quad_dot(Wout, sx, partial, RC0 + (blockIdx.x - 2048) * 4, t);
  }
}

// K4 (= old k_ctx2 + k_sm): ctx blocks recompute softmax from raw scores.
//  blocks [0,256): softmax reduce + 32-row ctx chunk (atomicAdd); block 0 writes attn
//  blocks [256, 256+NB_X): 16-row quads rows [38000, 50257)
__global__ __launch_bounds__(1024) void k_ctx2(
    const float* __restrict__ enc, const float* __restrict__ scores,
    float* __restrict__ ctx, const float* __restrict__ Wout,
    const float* __restrict__ hnew, float* __restrict__ partial,
    float* __restrict__ attn_out) {
  int t = threadIdx.x;
  if (blockIdx.x >= 256) {
    wout_h_16(Wout, hnew, partial, RX0 + ((int)blockIdx.x - 256) * 16, t);
    return;
  }
  __shared__ float red[16];
  __shared__ float bc[2];
  float vals[8];
  float m = -1e30f;
  #pragma unroll
  for (int u = 0; u < 8; ++u) { vals[u] = scores[u * 1024 + t]; m = fmaxf(m, vals[u]); }
  #pragma unroll
  for (int o = 32; o > 0; o >>= 1) m = fmaxf(m, __shfl_down(m, o, 64));
  if ((t & 63) == 0) red[t >> 6] = m;
  __syncthreads();
  if (t == 0) {
    float mm = red[0];
    #pragma unroll
    for (int k = 1; k < 16; ++k) mm = fmaxf(mm, red[k]);
    bc[0] = mm;
  }
  __syncthreads();
  m = bc[0];
  float s = 0.f;
  #pragma unroll
  for (int u = 0; u < 8; ++u) { vals[u] = __expf(vals[u] - m); s += vals[u]; }
  s = wave_reduce_sum(s);
  if ((t & 63) == 0) red[t >> 6] = s;
  __syncthreads();
  if (t == 0) {
    float ss = 0.f;
    #pragma unroll
    for (int k = 0; k < 16; ++k) ss += red[k];
    bc[1] = 1.f / ss;
  }
  __syncthreads();
  float inv = bc[1];
  if (blockIdx.x == 0) {
    #pragma unroll
    for (int u = 0; u < 8; ++u) attn_out[u * 1024 + t] = vals[u] * inv;
  }
  // own 32-row attn weights, then ctx accumulation
  __shared__ float sa[32];
  int s0 = blockIdx.x * 32;
  if (t < 32) sa[t] = __expf(scores[s0 + t] - m) * inv;
  __syncthreads();
  float acc = 0.f;
  #pragma unroll 8
  for (int j = 0; j < 32; ++j)
    acc += sa[j] * enc[(size_t)(s0 + j) * H + t];
  atomicAdd(&ctx[t], acc);
}

// K5: logits = partial + W_out[:,H:2H] @ ctx + b_out
__global__ __launch_bounds__(256) void k_logits(
    const float* __restrict__ Wout, const float* __restrict__ ctx,
    const float* __restrict__ partial, const float* __restrict__ bout,
    float* __restrict__ logits) {
  __shared__ float4 sx[256];
  int t = threadIdx.x;
  sx[t] = ((const float4*)ctx)[t];
  __syncthreads();
  int wave = t >> 6, lane = t & 63;
  int row = blockIdx.x * 4 + wave;
  if (row < V) {
    const float4* wr = (const float4*)Wout + (size_t)row * 512 + 256;
    float acc = 0.f;
    #pragma unroll
    for (int u = 0; u < 4; ++u) {
      float4 w = wr[lane + u * 64];
      float4 x = sx[lane + u * 64];
      acc += w.x * x.x + w.y * x.y + w.z * x.z + w.w * x.w;
    }
    acc = wave_reduce_sum(acc);
    if (lane == 0) logits[row] = acc + partial[row] + bout[row];
  }
}

extern "C" void kernel_launch(void* const* d_in, const int* in_sizes, int n_in,
                              void* d_out, int out_size, void* d_ws, size_t ws_size,
                              hipStream_t stream) {
  const int*   word  = (const int*)d_in[0];
  const float* h0    = (const float*)d_in[1];
  const float* enc   = (const float*)d_in[2];
  const float* emb   = (const float*)d_in[3];
  const float* Wattn = (const float*)d_in[4];
  const float* battn = (const float*)d_in[5];
  const float* Wih   = (const float*)d_in[6];
  const float* bih   = (const float*)d_in[7];
  const float* Whh   = (const float*)d_in[8];
  const float* bhh   = (const float*)d_in[9];
  const float* Wout  = (const float*)d_in[10];
  const float* bout  = (const float*)d_in[11];
  float* out = (float*)d_out;
  float* ws  = (float*)d_ws;

  float* gi      = ws;                  // 3072
  float* gh      = ws + 3072;           // 3072
  float* hnew    = ws + 6144;           // 1024
  float* v       = ws + 7168;           // 1024
  float* c0      = ws + 8192;           // 16
  float* scores  = ws + 8208;           // 8192 (raw scores)
  float* ctx     = ws + 16400;          // 1024
  float* partial = ws + 17424;          // 50257 (end ~67681 floats = 271 KB)

  k_gates <<<1536, 256, 0, stream>>>(Wih, Whh, bih, bhh, emb, word, h0, gi, gh, v, ctx);
  k_b     <<<32 + Q_B, 256, 0, stream>>>(Wattn, Wout, gi, gh, h0, battn,
                                         hnew, out + V, c0, v, partial);
  k_c     <<<2048 + Q_C, 256, 0, stream>>>(enc, v, c0, Wout, hnew, scores, partial);
  k_ctx2  <<<256 + NB_X, 1024, 0, stream>>>(enc, scores, ctx, Wout, hnew, partial,
                                            out + V + H);
  k_logits<<<(V + 3) / 4, 256, 0, stream>>>(Wout, ctx, partial, bout, out);
}